// Round 1
// baseline (11393.329 us; speedup 1.0000x reference)
//
#include <hip/hip_runtime.h>
#include <math.h>

#define N_NODES 100000
#define N_EDGES 6400000
#define THETA 1.0f
#define EQ_STEPS 100
#define N_STEPS 200
#define TOTAL_STEPS (EQ_STEPS + N_STEPS)

// ---------------- setup kernels (run once per launch) ----------------

__global__ void hist_kernel(const int* __restrict__ dst, int* __restrict__ counts) {
    int e = blockIdx.x * blockDim.x + threadIdx.x;
    if (e < N_EDGES) atomicAdd(&counts[dst[e]], 1);
}

// Single-block exclusive scan over 100k counts -> row offsets + scatter cursors.
__global__ void scan_kernel(const int* __restrict__ counts,
                            int* __restrict__ row_off,
                            int* __restrict__ cursor) {
    __shared__ int sums[1024];
    const int T = 1024;
    int t = threadIdx.x;
    int chunk = (N_NODES + T - 1) / T;       // 98
    int b = t * chunk;
    int e = b + chunk; if (e > N_NODES) e = N_NODES;
    int s = 0;
    for (int i = b; i < e; ++i) s += counts[i];
    sums[t] = s;
    __syncthreads();
    // Hillis-Steele inclusive scan
    for (int off = 1; off < T; off <<= 1) {
        int v = (t >= off) ? sums[t - off] : 0;
        __syncthreads();
        sums[t] += v;
        __syncthreads();
    }
    int base = (t == 0) ? 0 : sums[t - 1];   // exclusive prefix for this chunk
    for (int i = b; i < e; ++i) {
        row_off[i] = base;
        cursor[i]  = base;
        base += counts[i];
    }
    if (t == 0) row_off[N_NODES] = N_EDGES;
}

// Group edges by destination; pack {src, w} into 8 bytes.
__global__ void scatter_kernel(const int* __restrict__ src, const int* __restrict__ dst,
                               const float* __restrict__ W,
                               int* __restrict__ cursor, int2* __restrict__ edges) {
    int e = blockIdx.x * blockDim.x + threadIdx.x;
    if (e < N_EDGES) {
        int d = dst[e];
        int pos = atomicAdd(&cursor[d], 1);
        int2 pk;
        pk.x = src[e];
        pk.y = __float_as_int(W[e]);
        edges[pos] = pk;
    }
}

// ---------------- the per-step SpMV + sigmoid ----------------
// One wave64 per node: lanes stride the node's contiguous edge segment.
__global__ __launch_bounds__(256) void step_kernel(
        const int2* __restrict__ edges, const int* __restrict__ row_off,
        const float* __restrict__ s_in, float* __restrict__ s_out,
        float* __restrict__ out_row) {
    int wave = (blockIdx.x * blockDim.x + threadIdx.x) >> 6;
    int lane = threadIdx.x & 63;
    if (wave >= N_NODES) return;
    int beg = row_off[wave];
    int end = row_off[wave + 1];
    float acc = 0.f;
    for (int i = beg + lane; i < end; i += 64) {
        int2 pk = edges[i];
        acc += __int_as_float(pk.y) * s_in[pk.x];
    }
    // wave64 reduction
    for (int off = 32; off > 0; off >>= 1)
        acc += __shfl_down(acc, off, 64);
    if (lane == 0) {
        float v = 1.0f / (1.0f + __expf(-(acc - THETA)));
        s_out[wave] = v;
        if (out_row) out_row[wave] = v;
    }
}

extern "C" void kernel_launch(void* const* d_in, const int* in_sizes, int n_in,
                              void* d_out, int out_size, void* d_ws, size_t ws_size,
                              hipStream_t stream) {
    const float* x  = (const float*)d_in[0];            // (N_NODES,) initial state
    const float* W  = (const float*)d_in[1];            // (N_EDGES,)
    const int*   ei = (const int*)d_in[2];              // (2, N_EDGES) int
    const int*   src = ei;
    const int*   dst = ei + N_EDGES;
    // d_in[3] = n_steps (200), d_in[4] = equilibration_steps (100): fixed by
    // setup_inputs; hardcoded because reading device scalars on host would
    // require a sync that breaks graph capture.

    char* w = (char*)d_ws;
    // workspace layout (512B-aligned sections), total ~53.2 MB
    int*  counts  = (int*)(w + 0);                      // 100000 ints
    int*  row_off = (int*)(w + 400384);                 // 100001 ints
    int*  cursor  = (int*)(w + 800768);                 // 100000 ints
    int2* edges   = (int2*)(w + 1201152);               // 6.4M * 8B = 51,200,000
    float* s0     = (float*)(w + 52401152);             // 100000 floats
    float* s1     = (float*)(w + 52801536);             // 100000 floats

    hipMemsetAsync(counts, 0, N_NODES * sizeof(int), stream);

    const int EB = 256;
    const int EGRID = (N_EDGES + EB - 1) / EB;          // 25000
    hist_kernel<<<EGRID, EB, 0, stream>>>(dst, counts);
    scan_kernel<<<1, 1024, 0, stream>>>(counts, row_off, cursor);
    scatter_kernel<<<EGRID, EB, 0, stream>>>(src, dst, W, cursor, edges);

    // one wave (64 threads) per node, 4 nodes per 256-thread block
    const int SGRID = (N_NODES + 3) / 4;                // 25000
    float* outBase = (float*)d_out;
    const float* cur = x;                                // step 0 reads x directly
    float* bufs[2] = {s0, s1};
    for (int t = 0; t < TOTAL_STEPS; ++t) {
        float* nxt = bufs[t & 1];
        float* outrow = (t >= EQ_STEPS) ? (outBase + (size_t)(t - EQ_STEPS) * N_NODES)
                                        : nullptr;
        step_kernel<<<SGRID, 256, 0, stream>>>(edges, row_off, cur, nxt, outrow);
        cur = nxt;
    }
}